// Round 12
// baseline (119.417 us; speedup 1.0000x reference)
//
#include <hip/hip_runtime.h>
#include <cstddef>

namespace {

constexpr int IMG = 256;
constexpr long long N_ELEM = 16LL * 8 * IMG * IMG;   // 8388608

constexpr int NTHR   = 768;            // 12 waves = 12 row-teams
constexpr int STRIP  = 8;              // rows per thread; 12*8 = 96 compute rows
constexpr int DSTR   = 256;            // boundary row stride = full width
constexpr int DSLOTS = 24;             // 2 slots per wave (row0, row7)
constexpr int DBUF   = DSLOTS * DSTR;  // 6144 floats = 24 KB per buffer

constexpr float RP  = 3.9f;
constexpr float BET = 0.15f;
constexpr float KF  = 0.255f;          // 0.85 * 0.3  (folded conv coefficient)
constexpr float CF  = 0.595f;          // 0.85 * 0.7  (folded center coefficient)
constexpr float CLO = 1e-4f;
constexpr float CHI = (float)(1.0 - 1e-4);

__device__ __forceinline__ float mapf(float g) {
    float t = RP * g;
    return fmaf(-t, g, t);             // 3.9*g*(1-g), fused
}

// DPP wave-wide shifts: pure VALU, 0-fill at wave edge (= real image zero-pad).
__device__ __forceinline__ float dpp_up(float x) {
    return __int_as_float(__builtin_amdgcn_update_dpp(
        0, __float_as_int(x), 0x138, 0xf, 0xf, true));
}
__device__ __forceinline__ float dpp_dn(float x) {
    return __int_as_float(__builtin_amdgcn_update_dpp(
        0, __float_as_int(x), 0x130, 0xf, 0xf, true));
}

// folded update: g = med3(sum k2_i*m_i + 0.595*m_center + 0.15*dv, CLO, CHI)
__device__ __forceinline__ float px9(const float k2[9],
        float a0, float a1, float a2, float b0, float b1, float b2,
        float c0, float c1, float c2, float dvv) {
    float a = k2[0] * a0;
    a = fmaf(k2[1], a1, a); a = fmaf(k2[2], a2, a);
    a = fmaf(k2[3], b0, a); a = fmaf(k2[4], b1, a); a = fmaf(k2[5], b2, a);
    a = fmaf(k2[6], c0, a); a = fmaf(k2[7], c1, a); a = fmaf(k2[8], c2, a);
    a = fmaf(CF, b1, a);
    a = fmaf(BET, dvv, a);
    return __builtin_amdgcn_fmed3f(a, CLO, CHI);   // exact clamp, 1 inst
}

// 6-wide window from a full-width row quad: halos via DPP wave shifts.
#define WINQ(W, QX, QY, QZ, QW) {                       \
    W[1] = (QX); W[2] = (QY); W[3] = (QZ); W[4] = (QW); \
    W[0] = dpp_up(QW);                                  \
    W[5] = dpp_dn(QX);                                  \
}

// drive row I re-read from global (L2/L3-hot)
#define DVLD(I) (*(const float4*)(dp + (I) * IMG))

// one output row from windows WA(r-1), WB(r), WC(r+1); stats + STG in place.
#define ROWB(WA, WB, WC, DVE, SUM, SQ, STG, F) {                                           \
    float4 dv_ = (DVE);                                                                    \
    float g0 = px9(k2, WA[0],WA[1],WA[2], WB[0],WB[1],WB[2], WC[0],WC[1],WC[2], dv_.x);    \
    float g1 = px9(k2, WA[1],WA[2],WA[3], WB[1],WB[2],WB[3], WC[1],WC[2],WC[3], dv_.y);    \
    float g2 = px9(k2, WA[2],WA[3],WA[4], WB[2],WB[3],WB[4], WC[2],WC[3],WC[4], dv_.z);    \
    float g3 = px9(k2, WA[3],WA[4],WA[5], WB[3],WB[4],WB[5], WC[3],WC[4],WC[5], dv_.w);    \
    SUM.x += g0; SUM.y += g1; SUM.z += g2; SUM.w += g3;                                    \
    SQ.x = fmaf(g0,g0,SQ.x); SQ.y = fmaf(g1,g1,SQ.y);                                      \
    SQ.z = fmaf(g2,g2,SQ.z); SQ.w = fmaf(g3,g3,SQ.w);                                      \
    if (F) { STG.x = g0; STG.y = g1; STG.z = g2; STG.w = g3; }                             \
    else   { STG.x = mapf(g0); STG.y = mapf(g1); STG.z = mapf(g2); STG.w = mapf(g3); }     \
}

// one timestep: 2 boundary ds_reads, 8 rows in regs (dv re-read from L2),
// 2 boundary ds_writes.  Barrier placed by caller.  F=1: final (no writes)
#define STEP8(F, DR, DW) {                                                      \
    float4 qL, qR;                                                              \
    if (wv > 0)  qL = *(const float4*)((DR) + (2*wv - 1) * DSTR + c4);          \
    else { qL.x = 0.f; qL.y = 0.f; qL.z = 0.f; qL.w = 0.f; }                    \
    if (wv < 11) qR = *(const float4*)((DR) + (2*wv + 2) * DSTR + c4);          \
    else { qR.x = 0.f; qR.y = 0.f; qR.z = 0.f; qR.w = 0.f; }                    \
    float wA[6], wB[6], wC[6];                                                  \
    WINQ(wA, qL.x, qL.y, qL.z, qL.w)                                            \
    WINQ(wB, stg0.x, stg0.y, stg0.z, stg0.w)                                    \
    WINQ(wC, stg1.x, stg1.y, stg1.z, stg1.w)                                    \
    ROWB(wA, wB, wC, DVLD(0), sum0, sq0, stg0, F)                               \
    WINQ(wA, stg2.x, stg2.y, stg2.z, stg2.w)                                    \
    ROWB(wB, wC, wA, DVLD(1), sum1, sq1, stg1, F)                               \
    WINQ(wB, stg3.x, stg3.y, stg3.z, stg3.w)                                    \
    ROWB(wC, wA, wB, DVLD(2), sum2, sq2, stg2, F)                               \
    WINQ(wC, stg4.x, stg4.y, stg4.z, stg4.w)                                    \
    ROWB(wA, wB, wC, DVLD(3), sum3, sq3, stg3, F)                               \
    WINQ(wA, stg5.x, stg5.y, stg5.z, stg5.w)                                    \
    ROWB(wB, wC, wA, DVLD(4), sum4, sq4, stg4, F)                               \
    WINQ(wB, stg6.x, stg6.y, stg6.z, stg6.w)                                    \
    ROWB(wC, wA, wB, DVLD(5), sum5, sq5, stg5, F)                               \
    WINQ(wC, stg7.x, stg7.y, stg7.z, stg7.w)                                    \
    ROWB(wA, wB, wC, DVLD(6), sum6, sq6, stg6, F)                               \
    WINQ(wA, qR.x, qR.y, qR.z, qR.w)                                            \
    ROWB(wB, wC, wA, DVLD(7), sum7, sq7, stg7, F)                               \
    if (!(F)) {                                                                 \
        *(float4*)((DW) + (2*wv    ) * DSTR + c4) = stg0;                       \
        *(float4*)((DW) + (2*wv + 1) * DSTR + c4) = stg7;                       \
    }                                                                           \
}

__global__ __launch_bounds__(NTHR, 3)   // 12-wave WG = 3 waves/EU; 170-reg cap
void cml_kernel(const float* __restrict__ drive,
                const float* __restrict__ Kl,
                float* __restrict__ out)
{
    __shared__ __align__(16) float lds[2 * DBUF];   // 49152 B
    float* Da = lds;
    float* Db = lds + DBUF;

    const int bx   = blockIdx.x;
    const int img  = bx >> 2;              // 0..127  (b*8 + c)
    const int band = bx & 3;               // 4 bands, each 96 in-image rows
    // band geometry: all compute rows in-image; zero-pad only via qL/qR=0
    const int y0 = (band == 0) ? 0 : (band == 3 ? 160 : band * 64 - 16);
    const int os = (band == 0) ? 0 : (band == 3 ? 32 : 16);   // band-rel output rows
    const int oe = os + 63;

    const int tid  = threadIdx.x;
    const int lane = tid & 63;
    const int wv   = tid >> 6;             // 0..11
    const int c4   = lane * 4;

    // cone-of-influence deadline (erosion 1 row/step from band edges toward
    // the output window [os,oe]); real-pad sides auto-uncapped by the formula
    const int lim = min(15, min(8 * wv + 22 - os, oe + 15 - 8 * wv));

    const int ch = img & 7;
    float k2[9];
#pragma unroll
    for (int i = 0; i < 9; ++i)            // force SGPR (uniform per block)
        k2[i] = __int_as_float(__builtin_amdgcn_readfirstlane(
                    __float_as_int(KF * Kl[ch * 9 + i])));

    const float* dimg = drive + (size_t)img * (IMG * IMG);
    const float* dp   = dimg + (y0 + STRIP * wv) * IMG + c4;   // own drive rows

    float4 stg0,stg1,stg2,stg3,stg4,stg5,stg6,stg7;
    float4 sum0,sum1,sum2,sum3,sum4,sum5,sum6,sum7;
    float4 sq0,sq1,sq2,sq3,sq4,sq5,sq6,sq7;

#define INITROW(I) {                                                             \
    float4 t4 = DVLD(I);                                                         \
    stg##I.x = mapf(t4.x); stg##I.y = mapf(t4.y);                                \
    stg##I.z = mapf(t4.z); stg##I.w = mapf(t4.w);                                \
    sum##I.x = 0.f; sum##I.y = 0.f; sum##I.z = 0.f; sum##I.w = 0.f;              \
    sq##I = sum##I; }
    INITROW(0) INITROW(1) INITROW(2) INITROW(3)
    INITROW(4) INITROW(5) INITROW(6) INITROW(7)
#undef INITROW

    *(float4*)(Da + (2*wv    ) * DSTR + c4) = stg0;
    *(float4*)(Da + (2*wv + 1) * DSTR + c4) = stg7;
    __syncthreads();

    // ---- steps 0..13 (ping-pong, one barrier each; skip compute past lim)
#pragma unroll 1
    for (int s2 = 0; s2 < 7; ++s2) {
        if (2 * s2 < lim)     { STEP8(0, Da, Db) }
        __syncthreads();
        if (2 * s2 + 1 < lim) { STEP8(0, Db, Da) }
        __syncthreads();
    }
    // final step t=14 (reads state-14 in Da): exactly the output waves
    if (lim >= 15) { STEP8(1, Da, Db) }

    // ---- epilogue: per-row ownership check against [os,oe]
    const float inv15 = 1.0f / 15.0f;
#define EPI(I) { const int r = STRIP * wv + (I);                                  \
    if (r >= os && r <= oe) {                                                     \
        const int y = y0 + r;                                                     \
        size_t base = (size_t)img * (IMG*IMG) + (size_t)y * IMG + c4;             \
        float4 dvv = DVLD(I);                                                     \
        float mn0 = sum##I.x*inv15, mn1 = sum##I.y*inv15;                         \
        float mn2 = sum##I.z*inv15, mn3 = sum##I.w*inv15;                         \
        float4 m4; m4.x=mn0; m4.y=mn1; m4.z=mn2; m4.w=mn3;                        \
        float4 v4;                                                               \
        v4.x = fmaxf(fmaf(-mn0, mn0, sq##I.x*inv15), 0.f);                        \
        v4.y = fmaxf(fmaf(-mn1, mn1, sq##I.y*inv15), 0.f);                        \
        v4.z = fmaxf(fmaf(-mn2, mn2, sq##I.z*inv15), 0.f);                        \
        v4.w = fmaxf(fmaf(-mn3, mn3, sq##I.w*inv15), 0.f);                        \
        float4 d4; d4.x = stg##I.x - dvv.x; d4.y = stg##I.y - dvv.y;              \
        d4.z = stg##I.z - dvv.z; d4.w = stg##I.w - dvv.w;                         \
        *(float4*)(out + 0*N_ELEM + base) = stg##I;                               \
        *(float4*)(out + 1*N_ELEM + base) = m4;                                   \
        *(float4*)(out + 2*N_ELEM + base) = v4;                                   \
        *(float4*)(out + 3*N_ELEM + base) = d4;                                   \
        *(float4*)(out + 4*N_ELEM + base) = d4; } }
    EPI(0) EPI(1) EPI(2) EPI(3) EPI(4) EPI(5) EPI(6) EPI(7)
#undef EPI
}

} // namespace

extern "C" void kernel_launch(void* const* d_in, const int* in_sizes, int n_in,
                              void* d_out, int out_size, void* d_ws, size_t ws_size,
                              hipStream_t stream) {
    const float* drive = (const float*)d_in[0];
    const float* Kl    = (const float*)d_in[1];
    float* out         = (float*)d_out;
    (void)in_sizes; (void)n_in; (void)out_size; (void)d_ws; (void)ws_size;

    dim3 grid(128 * 4);   // 128 images * 4 bands
    dim3 block(NTHR);
    cml_kernel<<<grid, block, 0, stream>>>(drive, Kl, out);
}

// Round 13
// 97.001 us; speedup vs baseline: 1.2311x; 1.2311x over previous
//
#include <hip/hip_runtime.h>
#include <cstddef>

namespace {

constexpr int IMG = 256;
constexpr long long N_ELEM = 16LL * 8 * IMG * IMG;   // 8388608

constexpr int NTHR   = 1024;           // 16 waves = 16 row-teams
constexpr int DSTR   = 256;            // boundary row stride = full width
constexpr int DSLOTS = 32;             // 2 slots per wave (r_first, r_last)
constexpr int DBUF   = DSLOTS * DSTR;  // 8192 floats = 32 KB per buffer

constexpr float RP   = 3.9f;
constexpr float BET  = 0.15f;
constexpr float IBET = 1.0f / 0.15f;
constexpr float KF   = 0.255f;         // 0.85 * 0.3  (folded conv coefficient)
constexpr float CF   = 0.595f;         // 0.85 * 0.7  (folded center coefficient)
constexpr float CLO  = 1e-4f;
constexpr float CHI  = (float)(1.0 - 1e-4);

__device__ __forceinline__ float mapf(float g) {
    float t = RP * g;
    return fmaf(-t, g, t);             // 3.9*g*(1-g), fused
}

// DPP wave-wide shifts: pure VALU, 0-fill at wave edge (= real image zero-pad).
__device__ __forceinline__ float dpp_up(float x) {
    return __int_as_float(__builtin_amdgcn_update_dpp(
        0, __float_as_int(x), 0x138, 0xf, 0xf, true));
}
__device__ __forceinline__ float dpp_dn(float x) {
    return __int_as_float(__builtin_amdgcn_update_dpp(
        0, __float_as_int(x), 0x130, 0xf, 0xf, true));
}

// folded update: g = med3(bdv + sum k2_i*m_i + 0.595*m_center, CLO, CHI)
// (inputs finite -> med3 == clamp, bit-exact, 1 instruction)
__device__ __forceinline__ float px9(const float k2[9],
        float a0, float a1, float a2, float b0, float b1, float b2,
        float c0, float c1, float c2, float bdv) {
    float a = bdv;
    a = fmaf(k2[0], a0, a); a = fmaf(k2[1], a1, a); a = fmaf(k2[2], a2, a);
    a = fmaf(k2[3], b0, a); a = fmaf(k2[4], b1, a); a = fmaf(k2[5], b2, a);
    a = fmaf(k2[6], c0, a); a = fmaf(k2[7], c1, a); a = fmaf(k2[8], c2, a);
    a = fmaf(CF, b1, a);
    return __builtin_amdgcn_fmed3f(a, CLO, CHI);
}

// 6-wide window from a full-width row quad: halos via DPP wave shifts.
#define WINQ(W, QX, QY, QZ, QW) {                       \
    W[1] = (QX); W[2] = (QY); W[3] = (QZ); W[4] = (QW); \
    W[0] = dpp_up(QW);                                  \
    W[5] = dpp_dn(QX);                                  \
}

// one output row from windows WA(r-1), WB(r), WC(r+1); stats (gated by OWN,
// wave-uniform) + STG in place.
#define ROWB(WA, WB, WC, BDV, SUM, SQ, STG, OWN, F) {                                      \
    float g0 = px9(k2, WA[0],WA[1],WA[2], WB[0],WB[1],WB[2], WC[0],WC[1],WC[2], BDV.x);    \
    float g1 = px9(k2, WA[1],WA[2],WA[3], WB[1],WB[2],WB[3], WC[1],WC[2],WC[3], BDV.y);    \
    float g2 = px9(k2, WA[2],WA[3],WA[4], WB[2],WB[3],WB[4], WC[2],WC[3],WC[4], BDV.z);    \
    float g3 = px9(k2, WA[3],WA[4],WA[5], WB[3],WB[4],WB[5], WC[3],WC[4],WC[5], BDV.w);    \
    if (OWN) {                                                                             \
        SUM.x += g0; SUM.y += g1; SUM.z += g2; SUM.w += g3;                                \
        SQ.x = fmaf(g0,g0,SQ.x); SQ.y = fmaf(g1,g1,SQ.y);                                  \
        SQ.z = fmaf(g2,g2,SQ.z); SQ.w = fmaf(g3,g3,SQ.w);                                  \
    }                                                                                      \
    if (F) { STG.x = g0; STG.y = g1; STG.z = g2; STG.w = g3; }                             \
    else   { STG.x = mapf(g0); STG.y = mapf(g1); STG.z = mapf(g2); STG.w = mapf(g3); }     \
}

// boundary reads: wave w reads (w-1).r_last at slot 2w-1, (w+1).r_first at 2w+2
#define QLOAD(DR) \
    float4 qL, qR;                                                              \
    if (wv > 0)  qL = *(const float4*)((DR) + (2*wv - 1) * DSTR + c4);          \
    else { qL.x = 0.f; qL.y = 0.f; qL.z = 0.f; qL.w = 0.f; }                    \
    if (wv < 15) qR = *(const float4*)((DR) + (2*wv + 2) * DSTR + c4);          \
    else { qR.x = 0.f; qR.y = 0.f; qR.z = 0.f; qR.w = 0.f; }

// one timestep, STRIP=6 (interior): rows r0..r5 in regs, 2 boundary rows via LDS
#define STEP6(F, DR, DW) {                                                      \
    QLOAD(DR)                                                                   \
    float wA[6], wB[6], wC[6];                                                  \
    WINQ(wA, qL.x, qL.y, qL.z, qL.w)                                            \
    WINQ(wB, stg0.x, stg0.y, stg0.z, stg0.w)                                    \
    WINQ(wC, stg1.x, stg1.y, stg1.z, stg1.w)                                    \
    ROWB(wA, wB, wC, bdv0, sum0, sq0, stg0, ow0, F)                             \
    WINQ(wA, stg2.x, stg2.y, stg2.z, stg2.w)                                    \
    ROWB(wB, wC, wA, bdv1, sum1, sq1, stg1, ow1, F)                             \
    WINQ(wB, stg3.x, stg3.y, stg3.z, stg3.w)                                    \
    ROWB(wC, wA, wB, bdv2, sum2, sq2, stg2, ow2, F)                             \
    WINQ(wC, stg4.x, stg4.y, stg4.z, stg4.w)                                    \
    ROWB(wA, wB, wC, bdv3, sum3, sq3, stg3, ow3, F)                             \
    WINQ(wA, stg5.x, stg5.y, stg5.z, stg5.w)                                    \
    ROWB(wB, wC, wA, bdv4, sum4, sq4, stg4, ow4, F)                             \
    WINQ(wB, qR.x, qR.y, qR.z, qR.w)                                            \
    ROWB(wC, wA, wB, bdv5, sum5, sq5, stg5, ow5, F)                             \
    if (!(F)) {                                                                 \
        *(float4*)((DW) + (2*wv    ) * DSTR + c4) = stg0;                       \
        *(float4*)((DW) + (2*wv + 1) * DSTR + c4) = stg5;                       \
    }                                                                           \
}

// one timestep, STRIP=5 (edge bands)
#define STEP5(F, DR, DW) {                                                      \
    QLOAD(DR)                                                                   \
    float wA[6], wB[6], wC[6];                                                  \
    WINQ(wA, qL.x, qL.y, qL.z, qL.w)                                            \
    WINQ(wB, stg0.x, stg0.y, stg0.z, stg0.w)                                    \
    WINQ(wC, stg1.x, stg1.y, stg1.z, stg1.w)                                    \
    ROWB(wA, wB, wC, bdv0, sum0, sq0, stg0, ow0, F)                             \
    WINQ(wA, stg2.x, stg2.y, stg2.z, stg2.w)                                    \
    ROWB(wB, wC, wA, bdv1, sum1, sq1, stg1, ow1, F)                             \
    WINQ(wB, stg3.x, stg3.y, stg3.z, stg3.w)                                    \
    ROWB(wC, wA, wB, bdv2, sum2, sq2, stg2, ow2, F)                             \
    WINQ(wC, stg4.x, stg4.y, stg4.z, stg4.w)                                    \
    ROWB(wA, wB, wC, bdv3, sum3, sq3, stg3, ow3, F)                             \
    WINQ(wA, qR.x, qR.y, qR.z, qR.w)                                            \
    ROWB(wB, wC, wA, bdv4, sum4, sq4, stg4, ow4, F)                             \
    if (!(F)) {                                                                 \
        *(float4*)((DW) + (2*wv    ) * DSTR + c4) = stg0;                       \
        *(float4*)((DW) + (2*wv + 1) * DSTR + c4) = stg4;                       \
    }                                                                           \
}

#define INITROW(I, STRIDE) {                                                     \
    const int y = y0 + STRIDE * wv + (I);                                        \
    float4 t = *(const float4*)(dimg + y * IMG + c4);                            \
    stg##I.x = mapf(t.x); stg##I.y = mapf(t.y);                                  \
    stg##I.z = mapf(t.z); stg##I.w = mapf(t.w);                                  \
    bdv##I.x = BET * t.x; bdv##I.y = BET * t.y;                                  \
    bdv##I.z = BET * t.z; bdv##I.w = BET * t.w;                                  \
    sum##I.x = 0.f; sum##I.y = 0.f; sum##I.z = 0.f; sum##I.w = 0.f;              \
    sq##I = sum##I; }

#define EPISTORE(I) {                                                             \
    size_t base = (size_t)img * (IMG*IMG) + (size_t)y * IMG + c4;                 \
    float mn0 = sum##I.x*inv15, mn1 = sum##I.y*inv15;                             \
    float mn2 = sum##I.z*inv15, mn3 = sum##I.w*inv15;                             \
    float4 m4; m4.x=mn0; m4.y=mn1; m4.z=mn2; m4.w=mn3;                            \
    float4 v4;                                                                    \
    v4.x = fmaxf(fmaf(-mn0, mn0, sq##I.x*inv15), 0.f);                            \
    v4.y = fmaxf(fmaf(-mn1, mn1, sq##I.y*inv15), 0.f);                            \
    v4.z = fmaxf(fmaf(-mn2, mn2, sq##I.z*inv15), 0.f);                            \
    v4.w = fmaxf(fmaf(-mn3, mn3, sq##I.w*inv15), 0.f);                            \
    float4 d4;                                                                    \
    d4.x = fmaf(-bdv##I.x, IBET, stg##I.x); d4.y = fmaf(-bdv##I.y, IBET, stg##I.y);\
    d4.z = fmaf(-bdv##I.z, IBET, stg##I.z); d4.w = fmaf(-bdv##I.w, IBET, stg##I.w);\
    *(float4*)(out + 0*N_ELEM + base) = stg##I;                                   \
    *(float4*)(out + 1*N_ELEM + base) = m4;                                       \
    *(float4*)(out + 2*N_ELEM + base) = v4;                                       \
    *(float4*)(out + 3*N_ELEM + base) = d4;                                       \
    *(float4*)(out + 4*N_ELEM + base) = d4; }

// ---------------- interior bands (ty=1,2): 96 rows, STRIP=6 ----------------
__device__ __forceinline__ void run_int(const float* __restrict__ drive,
                                        const float* __restrict__ Kl,
                                        float* __restrict__ out,
                                        int img, int ty, float* __restrict__ lds)
{
    float* Da = lds;
    float* Db = lds + DBUF;
    const int tid  = threadIdx.x;
    const int lane = tid & 63;
    const int wv   = tid >> 6;                 // 0..15
    const int c4   = lane * 4;

    // cone deadlines: top lim = 6w+4, bottom lim = 6(15-w)+4, cap 15
    const int lt = 6 * wv + 4;
    const int lb = 6 * (15 - wv) + 4;
    const int lim = min(15, min(lt, lb));

    // stats ownership (wave-uniform): band-rel output rows are [16,79]
    const bool ow0 = (6*wv+0 >= 16) && (6*wv+0 <= 79);
    const bool ow1 = (6*wv+1 >= 16) && (6*wv+1 <= 79);
    const bool ow2 = (6*wv+2 >= 16) && (6*wv+2 <= 79);
    const bool ow3 = (6*wv+3 >= 16) && (6*wv+3 <= 79);
    const bool ow4 = (6*wv+4 >= 16) && (6*wv+4 <= 79);
    const bool ow5 = (6*wv+5 >= 16) && (6*wv+5 <= 79);

    const int ch = img & 7;
    float k2[9];
#pragma unroll
    for (int i = 0; i < 9; ++i) k2[i] = KF * Kl[ch * 9 + i];

    const float* dimg = drive + (size_t)img * (IMG * IMG);
    const int y0 = ty * 64 - 16;               // 48 or 112; all rows in-image

    float4 bdv0,bdv1,bdv2,bdv3,bdv4,bdv5;
    float4 stg0,stg1,stg2,stg3,stg4,stg5;
    float4 sum0,sum1,sum2,sum3,sum4,sum5;
    float4 sq0,sq1,sq2,sq3,sq4,sq5;

    INITROW(0,6) INITROW(1,6) INITROW(2,6) INITROW(3,6) INITROW(4,6) INITROW(5,6)

    *(float4*)(Da + (2*wv    ) * DSTR + c4) = stg0;
    *(float4*)(Da + (2*wv + 1) * DSTR + c4) = stg5;
    __syncthreads();

#pragma unroll 1
    for (int s2 = 0; s2 < 7; ++s2) {
        if (2 * s2 < lim)     { STEP6(0, Da, Db) }
        __syncthreads();
        if (2 * s2 + 1 < lim) { STEP6(0, Db, Da) }
        __syncthreads();
    }
    if (lim >= 15) { STEP6(1, Da, Db) }        // final step reads state-14 (in Da)

    if (wv >= 2 && wv <= 13) {
        const float inv15 = 1.0f / 15.0f;
#define EPI6(I) { const int r = 6*wv + (I);                                       \
        if (r >= 16 && r <= 79) { const int y = y0 + r; EPISTORE(I) } }
        EPI6(0) EPI6(1) EPI6(2) EPI6(3) EPI6(4) EPI6(5)
#undef EPI6
    }
}

// ---------------- edge bands (ty=0 TOP / ty=3 BOT): 80 rows, STRIP=5 --------
template<bool TOP>
__device__ __forceinline__ void run_edge(const float* __restrict__ drive,
                                         const float* __restrict__ Kl,
                                         float* __restrict__ out,
                                         int img, float* __restrict__ lds)
{
    float* Da = lds;
    float* Db = lds + DBUF;
    const int tid  = threadIdx.x;
    const int lane = tid & 63;
    const int wv   = tid >> 6;
    const int c4   = lane * 4;

    // TOP: real zero-pad at top, erosion from bottom -> lim = 78-5w
    // BOT: real zero-pad at bottom, erosion from top -> lim = 3+5w
    const int lim = TOP ? min(15, 78 - 5 * wv) : min(15, 3 + 5 * wv);

    // stats ownership: TOP outputs band-rel rows <=63, BOT rows >=16
    const bool ow0 = TOP ? (5*wv+0 <= 63) : (5*wv+0 >= 16);
    const bool ow1 = TOP ? (5*wv+1 <= 63) : (5*wv+1 >= 16);
    const bool ow2 = TOP ? (5*wv+2 <= 63) : (5*wv+2 >= 16);
    const bool ow3 = TOP ? (5*wv+3 <= 63) : (5*wv+3 >= 16);
    const bool ow4 = TOP ? (5*wv+4 <= 63) : (5*wv+4 >= 16);

    const int ch = img & 7;
    float k2[9];
#pragma unroll
    for (int i = 0; i < 9; ++i) k2[i] = KF * Kl[ch * 9 + i];

    const float* dimg = drive + (size_t)img * (IMG * IMG);
    const int y0 = TOP ? 0 : 176;              // rows 0..79 / 176..255, in-image

    float4 bdv0,bdv1,bdv2,bdv3,bdv4;
    float4 stg0,stg1,stg2,stg3,stg4;
    float4 sum0,sum1,sum2,sum3,sum4;
    float4 sq0,sq1,sq2,sq3,sq4;

    INITROW(0,5) INITROW(1,5) INITROW(2,5) INITROW(3,5) INITROW(4,5)

    *(float4*)(Da + (2*wv    ) * DSTR + c4) = stg0;
    *(float4*)(Da + (2*wv + 1) * DSTR + c4) = stg4;
    __syncthreads();

#pragma unroll 1
    for (int s2 = 0; s2 < 7; ++s2) {
        if (2 * s2 < lim)     { STEP5(0, Da, Db) }
        __syncthreads();
        if (2 * s2 + 1 < lim) { STEP5(0, Db, Da) }
        __syncthreads();
    }
    if (lim >= 15) { STEP5(1, Da, Db) }

    const bool own = TOP ? (wv <= 12) : (wv >= 3);
    if (own) {
        const float inv15 = 1.0f / 15.0f;
#define EPI5(I) { const int r = 5*wv + (I);                                       \
        if (TOP ? (r <= 63) : (r >= 16)) { const int y = y0 + r; EPISTORE(I) } }
        EPI5(0) EPI5(1) EPI5(2) EPI5(3) EPI5(4)
#undef EPI5
    }
}

__global__ __launch_bounds__(NTHR, 4)   // 16-wave WG = 4 waves/EU
void cml_kernel(const float* __restrict__ drive,
                const float* __restrict__ Kl,
                float* __restrict__ out)
{
    __shared__ __align__(16) float lds[2 * DBUF];   // 65536 B exactly
    const int bx  = blockIdx.x;
    const int img = bx >> 2;         // 0..127  (b*8 + c)
    const int t   = bx & 3;          // band
    if      (t == 0) run_edge<true >(drive, Kl, out, img, lds);
    else if (t == 3) run_edge<false>(drive, Kl, out, img, lds);
    else             run_int(drive, Kl, out, img, t, lds);
}

} // namespace

extern "C" void kernel_launch(void* const* d_in, const int* in_sizes, int n_in,
                              void* d_out, int out_size, void* d_ws, size_t ws_size,
                              hipStream_t stream) {
    const float* drive = (const float*)d_in[0];
    const float* Kl    = (const float*)d_in[1];
    float* out         = (float*)d_out;
    (void)in_sizes; (void)n_in; (void)out_size; (void)d_ws; (void)ws_size;

    dim3 grid(128 * 4);   // 128 images * 4 bands
    dim3 block(NTHR);
    cml_kernel<<<grid, block, 0, stream>>>(drive, Kl, out);
}